// Round 7
// baseline (1113.089 us; speedup 1.0000x reference)
//
#include <hip/hip_runtime.h>
#include <hip/hip_fp16.h>

#define HIDDEN 256

using bfrag = __attribute__((ext_vector_type(8))) short;   // 8 bf16 = 4 VGPRs
using facc4 = __attribute__((ext_vector_type(4))) float;   // 4 f32 accum

__device__ inline short bf16_rne(float x) {
  unsigned u = __builtin_bit_cast(unsigned, x);
  unsigned r = u + 0x7FFFu + ((u >> 16) & 1u);
  return (short)(r >> 16);
}
__device__ inline float bf16_to_f(short h) {
  unsigned u = ((unsigned)(unsigned short)h) << 16;
  return __builtin_bit_cast(float, u);
}
__device__ inline float h2f(unsigned short h) {
  return __half2float(__builtin_bit_cast(__half, h));
}

// ---------------------------------------------------------------------------
// CSR build: histogram over dst, exclusive scan, fill
// ---------------------------------------------------------------------------
__global__ __launch_bounds__(256) void k_hist(const int* __restrict__ dst,
                                              int* __restrict__ deg, int E) {
  for (int e = blockIdx.x * blockDim.x + threadIdx.x; e < E;
       e += gridDim.x * blockDim.x)
    atomicAdd(&deg[dst[e]], 1);
}

// 1-block scan: wave shuffle scans, 3 barriers per 1024-chunk
__global__ __launch_bounds__(1024) void k_scan(const int* __restrict__ deg,
                                               int* __restrict__ row_ptr, int N) {
  __shared__ int wsum[16];
  __shared__ int carry;
  const int t = threadIdx.x, lane = t & 63, w = t >> 6;
  if (t == 0) { carry = 0; row_ptr[0] = 0; }
  __syncthreads();
  for (int base = 0; base < N; base += 1024) {
    const int idx = base + t;
    int x = (idx < N) ? deg[idx] : 0;
#pragma unroll
    for (int off = 1; off < 64; off <<= 1) {
      int y = __shfl_up(x, off);
      if (lane >= off) x += y;
    }
    if (lane == 63) wsum[w] = x;
    __syncthreads();
    if (w == 0 && lane < 16) {
      int s = wsum[lane];
#pragma unroll
      for (int off = 1; off < 16; off <<= 1) {
        int y = __shfl_up(s, off);
        if (lane >= off) s += y;
      }
      wsum[lane] = s;
    }
    __syncthreads();
    const int total = wsum[15];
    const int inc = carry + (w > 0 ? wsum[w - 1] : 0) + x;
    if (idx < N) row_ptr[idx + 1] = inc;
    __syncthreads();
    if (t == 0) carry += total;
  }
}

__global__ __launch_bounds__(256) void k_dinv(const int* __restrict__ deg,
                                              float* __restrict__ dinv, int N) {
  int v = blockIdx.x * blockDim.x + threadIdx.x;
  if (v < N) dinv[v] = 1.0f / sqrtf((float)deg[v] + 1.0f);  // +1 self loop
}

__global__ __launch_bounds__(256) void k_fill(const int* __restrict__ src,
                                              const int* __restrict__ dst,
                                              const int* __restrict__ row_ptr,
                                              int* __restrict__ fill,
                                              int* __restrict__ csr, int E) {
  for (int e = blockIdx.x * blockDim.x + threadIdx.x; e < E;
       e += gridDim.x * blockDim.x) {
    int d = dst[e];
    int pos = atomicAdd(&fill[d], 1);
    csr[row_ptr[d] + pos] = src[e];
  }
}

// ---------------------------------------------------------------------------
// Weight prep: expand fp32 W into split-bf16, hi/lo-separated K-tile layout.
// Per 32-k tile: [hi: n=0..255 x kk=0..31 (8192 sh)][lo: 8192 sh] = 16384 sh.
// Wt offsets (shorts): W_in at 0 (24 tiles), layer l at 393216 + l*131072.
// ---------------------------------------------------------------------------
__global__ __launch_bounds__(256) void k_prep_w(const float* __restrict__ W_in,
                                                const float* __restrict__ W_g,
                                                short* __restrict__ Wt) {
  const int e = blockIdx.x * blockDim.x + threadIdx.x;
  if (e >= 196608 + 3 * 65536) return;
  float v;
  int k, n;
  size_t base;
  if (e < 196608) {           // W_in [768][256]
    k = e >> 8;
    n = e & 255;
    v = W_in[e];
    base = 0;
  } else {                    // W_g [3][256][256]
    int r = e - 196608;
    int lyr = r >> 16;
    k = (r >> 8) & 255;
    n = r & 255;
    v = W_g[r];
    base = 393216 + (size_t)lyr * 131072;
  }
  size_t pos = base + (size_t)(k >> 5) * 16384 + (size_t)n * 32 + (k & 31);
  short hi = bf16_rne(v);
  short lo = bf16_rne(v - bf16_to_f(hi));
  Wt[pos] = hi;
  Wt[pos + 8192] = lo;
}

// ---------------------------------------------------------------------------
// Split-bf16 MFMA GEMM v3: C[M,256] = A[M,K] @ B[K,256] (fp32 in).
// BM=64, BN=256, BK=64 fp32 (two 32-k chunks per barrier).
// 256 threads = 4 waves; wave w owns cols [64w,64w+64): 4x4 frags of 16x16x32.
// Per step: 1 barrier; ALL 16 B-frag loads issued up-front (chunk1's ride
// through chunk0's MFMA via counted vmcnt); A hi/lo staged in LDS
// double-buffer; next A tile (16 fp32/thread) prefetched during compute.
// 3 MFMAs per 32k: ah*bh + al*bh + ah*bl (al*bl ~2^-17, dropped).
// EPI==0: fp32 C = relu(A@B + bias[256]);  EPI==1: fp16 C = rowscale[r]*(A@B)
// ---------------------------------------------------------------------------
template <int EPI>
__global__ __launch_bounds__(256, 2) void gemm_mfma(const float* __restrict__ A,
                                                    const short* __restrict__ Wt,
                                                    const float* __restrict__ aux,
                                                    float* __restrict__ C,
                                                    int M, int K) {
  // row layout (shorts): [c0 hi 0..31][c0 lo 32..63][c1 hi 64..95][c1 lo 96..127][pad 8]
  __shared__ short As[2][64][136];
  const int t = threadIdx.x;
  const int w = t >> 6, l = t & 63;
  const int g = l >> 4, m16 = l & 15;
  const int row0 = blockIdx.x * 64;
  const int arow = t >> 2;
  const int ak4 = (t & 3) << 4;                       // fp32 k offset: 0,16,32,48
  const int wc = ((ak4 >> 5) << 6) + (ak4 & 16);      // hi short base; lo at +32

  facc4 acc[4][4];
#pragma unroll
  for (int i = 0; i < 4; ++i)
#pragma unroll
    for (int j = 0; j < 4; ++j) acc[i][j] = (facc4)(0.0f);

  const int nsteps = K >> 6;
  const int ga = row0 + arow;
  const bool aval = ga < M;
  const float* aptr = A + (size_t)ga * K + ak4;

  float4 f0 = make_float4(0.f, 0.f, 0.f, 0.f), f1 = f0, f2 = f0, f3 = f0;
  if (aval) {
    f0 = *(const float4*)(aptr + 0);
    f1 = *(const float4*)(aptr + 4);
    f2 = *(const float4*)(aptr + 8);
    f3 = *(const float4*)(aptr + 12);
  }

  int cur = 0;
  for (int s = 0; s < nsteps; ++s) {
    // --- convert 16 fp32 -> hi/lo bf16 (truncation split) and stage ---
    float av[16] = {f0.x, f0.y, f0.z, f0.w, f1.x, f1.y, f1.z, f1.w,
                    f2.x, f2.y, f2.z, f2.w, f3.x, f3.y, f3.z, f3.w};
    bfrag hia, hib, loa, lob;
#pragma unroll
    for (int i = 0; i < 8; ++i) {
      unsigned u = __builtin_bit_cast(unsigned, av[i]);
      hia[i] = (short)(u >> 16);
      float r = av[i] - __builtin_bit_cast(float, u & 0xFFFF0000u);
      loa[i] = (short)(__builtin_bit_cast(unsigned, r) >> 16);
      unsigned u2 = __builtin_bit_cast(unsigned, av[8 + i]);
      hib[i] = (short)(u2 >> 16);
      float r2 = av[8 + i] - __builtin_bit_cast(float, u2 & 0xFFFF0000u);
      lob[i] = (short)(__builtin_bit_cast(unsigned, r2) >> 16);
    }
    *(bfrag*)&As[cur][arow][wc] = hia;
    *(bfrag*)&As[cur][arow][wc + 8] = hib;
    *(bfrag*)&As[cur][arow][wc + 32] = loa;
    *(bfrag*)&As[cur][arow][wc + 40] = lob;
    // --- prefetch next A tile (in flight across whole compute phase) ---
    if (s + 1 < nsteps && aval) {
      const float* ap = aptr + (size_t)(s + 1) * 64;
      f0 = *(const float4*)(ap + 0);
      f1 = *(const float4*)(ap + 4);
      f2 = *(const float4*)(ap + 8);
      f3 = *(const float4*)(ap + 12);
    }
    __syncthreads();
    // --- all 16 B-frag loads issued up-front (L2-hot weights) ---
    const short* wb0 = Wt + ((size_t)(2 * s) << 14) + (size_t)(w * 64 + m16) * 32 + g * 8;
    const short* wb1 = wb0 + 16384;
    bfrag bh0[4], bl0[4], bh1[4], bl1[4];
#pragma unroll
    for (int nf = 0; nf < 4; ++nf) {
      bh0[nf] = *(const bfrag*)(wb0 + nf * 512);
      bl0[nf] = *(const bfrag*)(wb0 + nf * 512 + 8192);
    }
#pragma unroll
    for (int nf = 0; nf < 4; ++nf) {
      bh1[nf] = *(const bfrag*)(wb1 + nf * 512);
      bl1[nf] = *(const bfrag*)(wb1 + nf * 512 + 8192);
    }
    // --- chunk 0 ---
    bfrag ah[4], al[4];
#pragma unroll
    for (int mf = 0; mf < 4; ++mf) {
      ah[mf] = *(const bfrag*)&As[cur][mf * 16 + m16][g * 8];
      al[mf] = *(const bfrag*)&As[cur][mf * 16 + m16][32 + g * 8];
    }
#pragma unroll
    for (int nf = 0; nf < 4; ++nf)
#pragma unroll
      for (int mf = 0; mf < 4; ++mf)
        acc[mf][nf] = __builtin_amdgcn_mfma_f32_16x16x32_bf16(
            ah[mf], bh0[nf], acc[mf][nf], 0, 0, 0);
#pragma unroll
    for (int nf = 0; nf < 4; ++nf)
#pragma unroll
      for (int mf = 0; mf < 4; ++mf)
        acc[mf][nf] = __builtin_amdgcn_mfma_f32_16x16x32_bf16(
            al[mf], bh0[nf], acc[mf][nf], 0, 0, 0);
#pragma unroll
    for (int nf = 0; nf < 4; ++nf)
#pragma unroll
      for (int mf = 0; mf < 4; ++mf)
        acc[mf][nf] = __builtin_amdgcn_mfma_f32_16x16x32_bf16(
            ah[mf], bl0[nf], acc[mf][nf], 0, 0, 0);
    // --- chunk 1 ---
#pragma unroll
    for (int mf = 0; mf < 4; ++mf) {
      ah[mf] = *(const bfrag*)&As[cur][mf * 16 + m16][64 + g * 8];
      al[mf] = *(const bfrag*)&As[cur][mf * 16 + m16][96 + g * 8];
    }
#pragma unroll
    for (int nf = 0; nf < 4; ++nf)
#pragma unroll
      for (int mf = 0; mf < 4; ++mf)
        acc[mf][nf] = __builtin_amdgcn_mfma_f32_16x16x32_bf16(
            ah[mf], bh1[nf], acc[mf][nf], 0, 0, 0);
#pragma unroll
    for (int nf = 0; nf < 4; ++nf)
#pragma unroll
      for (int mf = 0; mf < 4; ++mf)
        acc[mf][nf] = __builtin_amdgcn_mfma_f32_16x16x32_bf16(
            al[mf], bh1[nf], acc[mf][nf], 0, 0, 0);
#pragma unroll
    for (int nf = 0; nf < 4; ++nf)
#pragma unroll
      for (int mf = 0; mf < 4; ++mf)
        acc[mf][nf] = __builtin_amdgcn_mfma_f32_16x16x32_bf16(
            ah[mf], bl1[nf], acc[mf][nf], 0, 0, 0);
    cur ^= 1;
  }
  // --- epilogue: D layout col=lane&15, row=(lane>>4)*4+reg ---
  const int colbase = w * 64;
  if (EPI == 0) {
#pragma unroll
    for (int nf = 0; nf < 4; ++nf) {
      const float bias = aux[colbase + nf * 16 + m16];
#pragma unroll
      for (int mf = 0; mf < 4; ++mf)
#pragma unroll
        for (int r = 0; r < 4; ++r) {
          int row = row0 + mf * 16 + g * 4 + r;
          if (row < M)
            C[(size_t)row * HIDDEN + colbase + nf * 16 + m16] =
                fmaxf(acc[mf][nf][r] + bias, 0.f);
        }
    }
  } else {
    __half* Ch = (__half*)C;   // fp16 m' for the gather
#pragma unroll
    for (int mf = 0; mf < 4; ++mf)
#pragma unroll
      for (int r = 0; r < 4; ++r) {
        int row = row0 + mf * 16 + g * 4 + r;
        if (row >= M) continue;
        const float sc = aux[row];
#pragma unroll
        for (int nf = 0; nf < 4; ++nf)
          Ch[(size_t)row * HIDDEN + colbase + nf * 16 + m16] =
              __float2half(acc[mf][nf][r] * sc);
      }
  }
}

// ---------------------------------------------------------------------------
// Gather aggregation + bias + BN + ReLU over fp16 m'.
// One wave per node; lane l owns channels 4l..4l+3 (8B = ushort4 per row).
// 8-edge unroll for memory-level parallelism.
// ---------------------------------------------------------------------------
__global__ __launch_bounds__(256) void k_aggregate(
    const unsigned short* __restrict__ mp, const int* __restrict__ row_ptr,
    const int* __restrict__ csr, const float* __restrict__ dinv,
    const float* __restrict__ bg, const float* __restrict__ gamma,
    const float* __restrict__ beta, const float* __restrict__ mean,
    const float* __restrict__ var, float* __restrict__ hout, int N) {
  const int wave = threadIdx.x >> 6, l = threadIdx.x & 63;
  const int v = blockIdx.x * 4 + wave;
  if (v >= N) return;
  const int co = l << 2;  // channel offset of this lane
  ushort4 rs = *(const ushort4*)(mp + (size_t)v * HIDDEN + co);  // self loop
  float4 acc;
  acc.x = h2f(rs.x); acc.y = h2f(rs.y); acc.z = h2f(rs.z); acc.w = h2f(rs.w);
  const int s = row_ptr[v], e = row_ptr[v + 1];
  int i = s;
  for (; i + 8 <= e; i += 8) {
    ushort4 r0 = *(const ushort4*)(mp + (size_t)csr[i + 0] * HIDDEN + co);
    ushort4 r1 = *(const ushort4*)(mp + (size_t)csr[i + 1] * HIDDEN + co);
    ushort4 r2 = *(const ushort4*)(mp + (size_t)csr[i + 2] * HIDDEN + co);
    ushort4 r3 = *(const ushort4*)(mp + (size_t)csr[i + 3] * HIDDEN + co);
    ushort4 r4 = *(const ushort4*)(mp + (size_t)csr[i + 4] * HIDDEN + co);
    ushort4 r5 = *(const ushort4*)(mp + (size_t)csr[i + 5] * HIDDEN + co);
    ushort4 r6 = *(const ushort4*)(mp + (size_t)csr[i + 6] * HIDDEN + co);
    ushort4 r7 = *(const ushort4*)(mp + (size_t)csr[i + 7] * HIDDEN + co);
    acc.x += h2f(r0.x) + h2f(r1.x) + h2f(r2.x) + h2f(r3.x) +
             h2f(r4.x) + h2f(r5.x) + h2f(r6.x) + h2f(r7.x);
    acc.y += h2f(r0.y) + h2f(r1.y) + h2f(r2.y) + h2f(r3.y) +
             h2f(r4.y) + h2f(r5.y) + h2f(r6.y) + h2f(r7.y);
    acc.z += h2f(r0.z) + h2f(r1.z) + h2f(r2.z) + h2f(r3.z) +
             h2f(r4.z) + h2f(r5.z) + h2f(r6.z) + h2f(r7.z);
    acc.w += h2f(r0.w) + h2f(r1.w) + h2f(r2.w) + h2f(r3.w) +
             h2f(r4.w) + h2f(r5.w) + h2f(r6.w) + h2f(r7.w);
  }
  for (; i < e; ++i) {
    ushort4 r0 = *(const ushort4*)(mp + (size_t)csr[i] * HIDDEN + co);
    acc.x += h2f(r0.x);
    acc.y += h2f(r0.y);
    acc.z += h2f(r0.z);
    acc.w += h2f(r0.w);
  }
  const float dv = dinv[v];
  float4 bg4 = *(const float4*)&bg[co];
  float4 g4 = *(const float4*)&gamma[co];
  float4 be4 = *(const float4*)&beta[co];
  float4 mn4 = *(const float4*)&mean[co];
  float4 vr4 = *(const float4*)&var[co];
  float4 o;
  o.x = fmaxf((acc.x * dv + bg4.x - mn4.x) * (g4.x / sqrtf(vr4.x + 1e-5f)) + be4.x, 0.f);
  o.y = fmaxf((acc.y * dv + bg4.y - mn4.y) * (g4.y / sqrtf(vr4.y + 1e-5f)) + be4.y, 0.f);
  o.z = fmaxf((acc.z * dv + bg4.z - mn4.z) * (g4.z / sqrtf(vr4.z + 1e-5f)) + be4.z, 0.f);
  o.w = fmaxf((acc.w * dv + bg4.w - mn4.w) * (g4.w / sqrtf(vr4.w + 1e-5f)) + be4.w, 0.f);
  ((float4*)hout)[(size_t)v * 64 + l] = o;
}

// ---------------------------------------------------------------------------
// Counts via binary search (batch is sorted by construction: jnp.sort)
// ---------------------------------------------------------------------------
__global__ __launch_bounds__(64) void k_count(const int* __restrict__ batch,
                                              float* __restrict__ cnt, int N,
                                              int G) {
  const int g = threadIdx.x;
  if (g >= G) return;
  int lo = 0, hi = N;
  while (lo < hi) {
    int mid = (lo + hi) >> 1;
    if (batch[mid] < g) lo = mid + 1; else hi = mid;
  }
  int lo2 = lo, hi2 = N;
  while (lo2 < hi2) {
    int mid = (lo2 + hi2) >> 1;
    if (batch[mid] < g + 1) lo2 = mid + 1; else hi2 = mid;
  }
  cnt[g] = (float)(lo2 - lo);
}

__global__ __launch_bounds__(256) void k_pool(const float* __restrict__ h,
                                              const int* __restrict__ batch,
                                              float* __restrict__ sums, int N) {
  const int t = threadIdx.x;
  const int start = blockIdx.x * 256;
  if (start >= N) return;
  const int end = min(start + 256, N);
  float acc = 0.f;
  int cur = batch[start];
  for (int n = start; n < end; ++n) {
    int g = batch[n];
    if (g != cur) {
      atomicAdd(&sums[cur * HIDDEN + t], acc);
      acc = 0.f;
      cur = g;
    }
    acc += h[(size_t)n * HIDDEN + t];
  }
  atomicAdd(&sums[cur * HIDDEN + t], acc);
}

// ---------------------------------------------------------------------------
// Head MLP: out = relu(g@W1+b1)@W2+b2, one block per graph
// ---------------------------------------------------------------------------
__global__ __launch_bounds__(128) void k_head(const float* __restrict__ sums,
                                              const float* __restrict__ cnt,
                                              const float* __restrict__ W1,
                                              const float* __restrict__ b1,
                                              const float* __restrict__ W2,
                                              const float* __restrict__ b2,
                                              float* __restrict__ out) {
  __shared__ float gr[256];
  __shared__ float t1[128];
  const int b = blockIdx.x, t = threadIdx.x;
  const float inv = 1.0f / fmaxf(cnt[b], 1.0f);
  gr[t] = sums[b * HIDDEN + t] * inv;
  gr[t + 128] = sums[b * HIDDEN + t + 128] * inv;
  __syncthreads();
  float a = b1[t];
  for (int k = 0; k < 256; ++k) a += gr[k] * W1[k * 128 + t];
  t1[t] = fmaxf(a, 0.f);
  __syncthreads();
  float o = b2[t];
  for (int k = 0; k < 128; ++k) o += t1[k] * W2[k * 128 + t];
  out[b * 128 + t] = o;
}

// ---------------------------------------------------------------------------
extern "C" void kernel_launch(void* const* d_in, const int* in_sizes, int n_in,
                              void* d_out, int out_size, void* d_ws,
                              size_t ws_size, hipStream_t stream) {
  (void)n_in;
  (void)ws_size;
  const float* x = (const float*)d_in[0];
  const int* ei = (const int*)d_in[1];
  const int* batch = (const int*)d_in[2];
  const float* W_in = (const float*)d_in[3];
  const float* b_in = (const float*)d_in[4];
  const float* W_g = (const float*)d_in[5];
  const float* b_g = (const float*)d_in[6];
  const float* bn_gamma = (const float*)d_in[7];
  const float* bn_beta = (const float*)d_in[8];
  const float* bn_mean = (const float*)d_in[9];
  const float* bn_var = (const float*)d_in[10];
  const float* W1 = (const float*)d_in[11];
  const float* b1 = (const float*)d_in[12];
  const float* W2 = (const float*)d_in[13];
  const float* b2 = (const float*)d_in[14];

  const int KIN = 768;
  const int N = in_sizes[0] / KIN;   // 100000
  const int E = in_sizes[1] / 2;     // 1600000
  const int G = out_size / 128;      // 64

  const int* src = ei;
  const int* dst = ei + E;

  char* ws = (char*)d_ws;
  size_t off = 0;
  auto take = [&](size_t bytes) -> void* {
    void* p = ws + off;
    off += (bytes + 255) & ~(size_t)255;
    return p;
  };
  float* h0 = (float*)take((size_t)N * HIDDEN * 4);
  unsigned short* h1 = (unsigned short*)take((size_t)N * HIDDEN * 2);  // fp16 m'
  float* dinv = (float*)take((size_t)N * 4);
  int* deg = (int*)take((size_t)N * 4);
  int* fill = (int*)take((size_t)N * 4);
  int* row_ptr = (int*)take((size_t)(N + 1) * 4);
  int* csr = (int*)take((size_t)E * 4);
  float* sums = (float*)take((size_t)G * HIDDEN * 4);
  float* cnt = (float*)take((size_t)G * 4);
  short* Wt = (short*)take((size_t)(393216 + 3 * 131072) * 2);

  hipMemsetAsync(deg, 0, (size_t)N * 4, stream);
  hipMemsetAsync(fill, 0, (size_t)N * 4, stream);
  hipMemsetAsync(sums, 0, (size_t)G * HIDDEN * 4, stream);

  k_prep_w<<<(196608 + 3 * 65536 + 255) / 256, 256, 0, stream>>>(W_in, W_g, Wt);
  k_hist<<<2048, 256, 0, stream>>>(dst, deg, E);
  k_scan<<<1, 1024, 0, stream>>>(deg, row_ptr, N);
  k_dinv<<<(N + 255) / 256, 256, 0, stream>>>(deg, dinv, N);
  k_fill<<<2048, 256, 0, stream>>>(src, dst, row_ptr, fill, csr, E);

  const int gx = (N + 63) / 64;
  gemm_mfma<0><<<gx, 256, 0, stream>>>(x, Wt, b_in, h0, N, KIN);
  for (int i = 0; i < 3; ++i) {
    gemm_mfma<1><<<gx, 256, 0, stream>>>(h0, Wt + 393216 + (size_t)i * 131072,
                                         dinv, (float*)h1, N, HIDDEN);
    k_aggregate<<<(N + 3) / 4, 256, 0, stream>>>(
        h1, row_ptr, csr, dinv, b_g + i * HIDDEN, bn_gamma + i * HIDDEN,
        bn_beta + i * HIDDEN, bn_mean + i * HIDDEN, bn_var + i * HIDDEN, h0, N);
  }
  k_count<<<1, 64, 0, stream>>>(batch, cnt, N, G);
  k_pool<<<(N + 255) / 256, 256, 0, stream>>>(h0, batch, sums, N);
  k_head<<<G, 128, 0, stream>>>(sums, cnt, W1, b1, W2, b2, (float*)d_out);
}

// Round 8
// 1090.373 us; speedup vs baseline: 1.0208x; 1.0208x over previous
//
#include <hip/hip_runtime.h>
#include <hip/hip_fp16.h>

#define HIDDEN 256

using bfrag = __attribute__((ext_vector_type(8))) short;   // 8 bf16 = 4 VGPRs
using facc4 = __attribute__((ext_vector_type(4))) float;   // 4 f32 accum

__device__ inline short bf16_rne(float x) {
  unsigned u = __builtin_bit_cast(unsigned, x);
  unsigned r = u + 0x7FFFu + ((u >> 16) & 1u);
  return (short)(r >> 16);
}
__device__ inline float bf16_to_f(short h) {
  unsigned u = ((unsigned)(unsigned short)h) << 16;
  return __builtin_bit_cast(float, u);
}
__device__ inline float h2f(unsigned short h) {
  return __half2float(__builtin_bit_cast(__half, h));
}

// ---------------------------------------------------------------------------
// CSR build: histogram over dst, exclusive scan, fill
// ---------------------------------------------------------------------------
__global__ __launch_bounds__(256) void k_hist(const int* __restrict__ dst,
                                              int* __restrict__ deg, int E) {
  for (int e = blockIdx.x * blockDim.x + threadIdx.x; e < E;
       e += gridDim.x * blockDim.x)
    atomicAdd(&deg[dst[e]], 1);
}

// 1-block scan: wave shuffle scans, 3 barriers per 1024-chunk
__global__ __launch_bounds__(1024) void k_scan(const int* __restrict__ deg,
                                               int* __restrict__ row_ptr, int N) {
  __shared__ int wsum[16];
  __shared__ int carry;
  const int t = threadIdx.x, lane = t & 63, w = t >> 6;
  if (t == 0) { carry = 0; row_ptr[0] = 0; }
  __syncthreads();
  for (int base = 0; base < N; base += 1024) {
    const int idx = base + t;
    int x = (idx < N) ? deg[idx] : 0;
#pragma unroll
    for (int off = 1; off < 64; off <<= 1) {
      int y = __shfl_up(x, off);
      if (lane >= off) x += y;
    }
    if (lane == 63) wsum[w] = x;
    __syncthreads();
    if (w == 0 && lane < 16) {
      int s = wsum[lane];
#pragma unroll
      for (int off = 1; off < 16; off <<= 1) {
        int y = __shfl_up(s, off);
        if (lane >= off) s += y;
      }
      wsum[lane] = s;
    }
    __syncthreads();
    const int total = wsum[15];
    const int inc = carry + (w > 0 ? wsum[w - 1] : 0) + x;
    if (idx < N) row_ptr[idx + 1] = inc;
    __syncthreads();
    if (t == 0) carry += total;
  }
}

__global__ __launch_bounds__(256) void k_dinv(const int* __restrict__ deg,
                                              float* __restrict__ dinv, int N) {
  int v = blockIdx.x * blockDim.x + threadIdx.x;
  if (v < N) dinv[v] = 1.0f / sqrtf((float)deg[v] + 1.0f);  // +1 self loop
}

__global__ __launch_bounds__(256) void k_fill(const int* __restrict__ src,
                                              const int* __restrict__ dst,
                                              const int* __restrict__ row_ptr,
                                              int* __restrict__ fill,
                                              int* __restrict__ csr, int E) {
  for (int e = blockIdx.x * blockDim.x + threadIdx.x; e < E;
       e += gridDim.x * blockDim.x) {
    int d = dst[e];
    int pos = atomicAdd(&fill[d], 1);
    csr[row_ptr[d] + pos] = src[e];
  }
}

// ---------------------------------------------------------------------------
// Weight prep: expand fp32 W into split-bf16, hi/lo-separated K-tile layout.
// Per 32-k tile: [hi: n=0..255 x kk=0..31 (8192 sh)][lo: 8192 sh] = 16384 sh.
// Wt offsets (shorts): W_in at 0 (24 tiles), layer l at 393216 + l*131072.
// ---------------------------------------------------------------------------
__global__ __launch_bounds__(256) void k_prep_w(const float* __restrict__ W_in,
                                                const float* __restrict__ W_g,
                                                short* __restrict__ Wt) {
  const int e = blockIdx.x * blockDim.x + threadIdx.x;
  if (e >= 196608 + 3 * 65536) return;
  float v;
  int k, n;
  size_t base;
  if (e < 196608) {           // W_in [768][256]
    k = e >> 8;
    n = e & 255;
    v = W_in[e];
    base = 0;
  } else {                    // W_g [3][256][256]
    int r = e - 196608;
    int lyr = r >> 16;
    k = (r >> 8) & 255;
    n = r & 255;
    v = W_g[r];
    base = 393216 + (size_t)lyr * 131072;
  }
  size_t pos = base + (size_t)(k >> 5) * 16384 + (size_t)n * 32 + (k & 31);
  short hi = bf16_rne(v);
  short lo = bf16_rne(v - bf16_to_f(hi));
  Wt[pos] = hi;
  Wt[pos + 8192] = lo;
}

// ---------------------------------------------------------------------------
// Split-bf16 MFMA GEMM v4: C[M,256] = A[M,K] @ B[K,256] (fp32 in).
// BM=128, BN=256, BK=32. 256 threads = 4 waves; wave w owns a 128x64 slab
// (cols [64w,64w+64)): 8x4 frags of 16x16x32 -> 128 AGPR acc, 2x B reuse
// vs BM=64. Per step: 1 barrier; 8 B-frag loads (L2-hot Wt, no B LDS);
// A hi/lo in LDS dbuf; next A tile prefetched to regs during compute.
// 3 MFMAs per 32k: ah*bh + ah*bl + al*bh (al*bl ~2^-17 dropped); af regs
// reused hi->lo to cap VGPR.
// EPI==0: fp32 C = relu(A@B + bias[256]);  EPI==1: fp16 C = rowscale[r]*(A@B)
// ---------------------------------------------------------------------------
template <int EPI>
__global__ __launch_bounds__(256, 2) void gemm_mfma(const float* __restrict__ A,
                                                    const short* __restrict__ Wt,
                                                    const float* __restrict__ aux,
                                                    float* __restrict__ C,
                                                    int M, int K) {
  // row layout (shorts): [hi k0..31][lo k32..63][pad 8] stride 72
  __shared__ short As[2][128][72];
  const int t = threadIdx.x;
  const int w = t >> 6, l = t & 63;
  const int g = l >> 4, m16 = l & 15;
  const int row0 = blockIdx.x * 128;
  const int arow = t >> 1;                 // staging row (2 threads/row)
  const int ks = (t & 1) << 4;             // fp32 k offset: 0 or 16

  facc4 acc[8][4];
#pragma unroll
  for (int i = 0; i < 8; ++i)
#pragma unroll
    for (int j = 0; j < 4; ++j) acc[i][j] = (facc4)(0.0f);

  const int nsteps = K >> 5;
  const int ga = row0 + arow;
  const bool aval = ga < M;
  const float* aptr = A + (size_t)ga * K + ks;

  float4 f0 = make_float4(0.f, 0.f, 0.f, 0.f), f1 = f0, f2 = f0, f3 = f0;
  if (aval) {
    f0 = *(const float4*)(aptr + 0);
    f1 = *(const float4*)(aptr + 4);
    f2 = *(const float4*)(aptr + 8);
    f3 = *(const float4*)(aptr + 12);
  }

  int cur = 0;
  for (int s = 0; s < nsteps; ++s) {
    // --- convert 16 fp32 -> hi/lo bf16 (truncation split) and stage ---
    float av[16] = {f0.x, f0.y, f0.z, f0.w, f1.x, f1.y, f1.z, f1.w,
                    f2.x, f2.y, f2.z, f2.w, f3.x, f3.y, f3.z, f3.w};
    bfrag hia, hib, loa, lob;
#pragma unroll
    for (int i = 0; i < 8; ++i) {
      unsigned u = __builtin_bit_cast(unsigned, av[i]);
      hia[i] = (short)(u >> 16);
      float r = av[i] - __builtin_bit_cast(float, u & 0xFFFF0000u);
      loa[i] = (short)(__builtin_bit_cast(unsigned, r) >> 16);
      unsigned u2 = __builtin_bit_cast(unsigned, av[8 + i]);
      hib[i] = (short)(u2 >> 16);
      float r2 = av[8 + i] - __builtin_bit_cast(float, u2 & 0xFFFF0000u);
      lob[i] = (short)(__builtin_bit_cast(unsigned, r2) >> 16);
    }
    *(bfrag*)&As[cur][arow][ks] = hia;
    *(bfrag*)&As[cur][arow][ks + 8] = hib;
    *(bfrag*)&As[cur][arow][32 + ks] = loa;
    *(bfrag*)&As[cur][arow][32 + ks + 8] = lob;
    // --- prefetch next A tile (in flight across whole compute phase) ---
    if (s + 1 < nsteps && aval) {
      const float* ap = aptr + (size_t)(s + 1) * 32;
      f0 = *(const float4*)(ap + 0);
      f1 = *(const float4*)(ap + 4);
      f2 = *(const float4*)(ap + 8);
      f3 = *(const float4*)(ap + 12);
    }
    __syncthreads();
    // --- 8 B-frag loads up-front (L2-hot weights) ---
    const short* wb = Wt + ((size_t)s << 14) + (size_t)(w * 64 + m16) * 32 + g * 8;
    bfrag bh[4], bl[4];
#pragma unroll
    for (int nf = 0; nf < 4; ++nf) {
      bh[nf] = *(const bfrag*)(wb + nf * 512);
      bl[nf] = *(const bfrag*)(wb + nf * 512 + 8192);
    }
    // --- pass 1+2: ah x bh, ah x bl (af regs hold hi) ---
    bfrag af[8];
#pragma unroll
    for (int mf = 0; mf < 8; ++mf)
      af[mf] = *(const bfrag*)&As[cur][mf * 16 + m16][g * 8];
#pragma unroll
    for (int nf = 0; nf < 4; ++nf)
#pragma unroll
      for (int mf = 0; mf < 8; ++mf)
        acc[mf][nf] = __builtin_amdgcn_mfma_f32_16x16x32_bf16(
            af[mf], bh[nf], acc[mf][nf], 0, 0, 0);
#pragma unroll
    for (int nf = 0; nf < 4; ++nf)
#pragma unroll
      for (int mf = 0; mf < 8; ++mf)
        acc[mf][nf] = __builtin_amdgcn_mfma_f32_16x16x32_bf16(
            af[mf], bl[nf], acc[mf][nf], 0, 0, 0);
    // --- pass 3: al x bh (af regs reused for lo) ---
#pragma unroll
    for (int mf = 0; mf < 8; ++mf)
      af[mf] = *(const bfrag*)&As[cur][mf * 16 + m16][32 + g * 8];
#pragma unroll
    for (int nf = 0; nf < 4; ++nf)
#pragma unroll
      for (int mf = 0; mf < 8; ++mf)
        acc[mf][nf] = __builtin_amdgcn_mfma_f32_16x16x32_bf16(
            af[mf], bh[nf], acc[mf][nf], 0, 0, 0);
    cur ^= 1;
  }
  // --- epilogue: D layout col=lane&15, row=(lane>>4)*4+reg ---
  const int colbase = w * 64;
  if (EPI == 0) {
#pragma unroll
    for (int nf = 0; nf < 4; ++nf) {
      const float bias = aux[colbase + nf * 16 + m16];
#pragma unroll
      for (int mf = 0; mf < 8; ++mf)
#pragma unroll
        for (int r = 0; r < 4; ++r) {
          int row = row0 + mf * 16 + g * 4 + r;
          if (row < M)
            C[(size_t)row * HIDDEN + colbase + nf * 16 + m16] =
                fmaxf(acc[mf][nf][r] + bias, 0.f);
        }
    }
  } else {
    __half* Ch = (__half*)C;   // fp16 m' for the gather
#pragma unroll
    for (int mf = 0; mf < 8; ++mf)
#pragma unroll
      for (int r = 0; r < 4; ++r) {
        int row = row0 + mf * 16 + g * 4 + r;
        if (row >= M) continue;
        const float sc = aux[row];
#pragma unroll
        for (int nf = 0; nf < 4; ++nf)
          Ch[(size_t)row * HIDDEN + colbase + nf * 16 + m16] =
              __float2half(acc[mf][nf][r] * sc);
      }
  }
}

// ---------------------------------------------------------------------------
// Gather aggregation + bias + BN + ReLU over fp16 m'.
// One wave per node; lane l owns channels 4l..4l+3 (8B = ushort4 per row).
// 8-edge unroll for memory-level parallelism.
// ---------------------------------------------------------------------------
__global__ __launch_bounds__(256) void k_aggregate(
    const unsigned short* __restrict__ mp, const int* __restrict__ row_ptr,
    const int* __restrict__ csr, const float* __restrict__ dinv,
    const float* __restrict__ bg, const float* __restrict__ gamma,
    const float* __restrict__ beta, const float* __restrict__ mean,
    const float* __restrict__ var, float* __restrict__ hout, int N) {
  const int wave = threadIdx.x >> 6, l = threadIdx.x & 63;
  const int v = blockIdx.x * 4 + wave;
  if (v >= N) return;
  const int co = l << 2;  // channel offset of this lane
  ushort4 rs = *(const ushort4*)(mp + (size_t)v * HIDDEN + co);  // self loop
  float4 acc;
  acc.x = h2f(rs.x); acc.y = h2f(rs.y); acc.z = h2f(rs.z); acc.w = h2f(rs.w);
  const int s = row_ptr[v], e = row_ptr[v + 1];
  int i = s;
  for (; i + 8 <= e; i += 8) {
    ushort4 r0 = *(const ushort4*)(mp + (size_t)csr[i + 0] * HIDDEN + co);
    ushort4 r1 = *(const ushort4*)(mp + (size_t)csr[i + 1] * HIDDEN + co);
    ushort4 r2 = *(const ushort4*)(mp + (size_t)csr[i + 2] * HIDDEN + co);
    ushort4 r3 = *(const ushort4*)(mp + (size_t)csr[i + 3] * HIDDEN + co);
    ushort4 r4 = *(const ushort4*)(mp + (size_t)csr[i + 4] * HIDDEN + co);
    ushort4 r5 = *(const ushort4*)(mp + (size_t)csr[i + 5] * HIDDEN + co);
    ushort4 r6 = *(const ushort4*)(mp + (size_t)csr[i + 6] * HIDDEN + co);
    ushort4 r7 = *(const ushort4*)(mp + (size_t)csr[i + 7] * HIDDEN + co);
    acc.x += h2f(r0.x) + h2f(r1.x) + h2f(r2.x) + h2f(r3.x) +
             h2f(r4.x) + h2f(r5.x) + h2f(r6.x) + h2f(r7.x);
    acc.y += h2f(r0.y) + h2f(r1.y) + h2f(r2.y) + h2f(r3.y) +
             h2f(r4.y) + h2f(r5.y) + h2f(r6.y) + h2f(r7.y);
    acc.z += h2f(r0.z) + h2f(r1.z) + h2f(r2.z) + h2f(r3.z) +
             h2f(r4.z) + h2f(r5.z) + h2f(r6.z) + h2f(r7.z);
    acc.w += h2f(r0.w) + h2f(r1.w) + h2f(r2.w) + h2f(r3.w) +
             h2f(r4.w) + h2f(r5.w) + h2f(r6.w) + h2f(r7.w);
  }
  for (; i < e; ++i) {
    ushort4 r0 = *(const ushort4*)(mp + (size_t)csr[i] * HIDDEN + co);
    acc.x += h2f(r0.x);
    acc.y += h2f(r0.y);
    acc.z += h2f(r0.z);
    acc.w += h2f(r0.w);
  }
  const float dv = dinv[v];
  float4 bg4 = *(const float4*)&bg[co];
  float4 g4 = *(const float4*)&gamma[co];
  float4 be4 = *(const float4*)&beta[co];
  float4 mn4 = *(const float4*)&mean[co];
  float4 vr4 = *(const float4*)&var[co];
  float4 o;
  o.x = fmaxf((acc.x * dv + bg4.x - mn4.x) * (g4.x / sqrtf(vr4.x + 1e-5f)) + be4.x, 0.f);
  o.y = fmaxf((acc.y * dv + bg4.y - mn4.y) * (g4.y / sqrtf(vr4.y + 1e-5f)) + be4.y, 0.f);
  o.z = fmaxf((acc.z * dv + bg4.z - mn4.z) * (g4.z / sqrtf(vr4.z + 1e-5f)) + be4.z, 0.f);
  o.w = fmaxf((acc.w * dv + bg4.w - mn4.w) * (g4.w / sqrtf(vr4.w + 1e-5f)) + be4.w, 0.f);
  ((float4*)hout)[(size_t)v * 64 + l] = o;
}

// ---------------------------------------------------------------------------
// Counts via binary search (batch is sorted by construction: jnp.sort)
// ---------------------------------------------------------------------------
__global__ __launch_bounds__(64) void k_count(const int* __restrict__ batch,
                                              float* __restrict__ cnt, int N,
                                              int G) {
  const int g = threadIdx.x;
  if (g >= G) return;
  int lo = 0, hi = N;
  while (lo < hi) {
    int mid = (lo + hi) >> 1;
    if (batch[mid] < g) lo = mid + 1; else hi = mid;
  }
  int lo2 = lo, hi2 = N;
  while (lo2 < hi2) {
    int mid = (lo2 + hi2) >> 1;
    if (batch[mid] < g + 1) lo2 = mid + 1; else hi2 = mid;
  }
  cnt[g] = (float)(lo2 - lo);
}

__global__ __launch_bounds__(256) void k_pool(const float* __restrict__ h,
                                              const int* __restrict__ batch,
                                              float* __restrict__ sums, int N) {
  const int t = threadIdx.x;
  const int start = blockIdx.x * 256;
  if (start >= N) return;
  const int end = min(start + 256, N);
  float acc = 0.f;
  int cur = batch[start];
  for (int n = start; n < end; ++n) {
    int g = batch[n];
    if (g != cur) {
      atomicAdd(&sums[cur * HIDDEN + t], acc);
      acc = 0.f;
      cur = g;
    }
    acc += h[(size_t)n * HIDDEN + t];
  }
  atomicAdd(&sums[cur * HIDDEN + t], acc);
}

// ---------------------------------------------------------------------------
// Head MLP: out = relu(g@W1+b1)@W2+b2, one block per graph
// ---------------------------------------------------------------------------
__global__ __launch_bounds__(128) void k_head(const float* __restrict__ sums,
                                              const float* __restrict__ cnt,
                                              const float* __restrict__ W1,
                                              const float* __restrict__ b1,
                                              const float* __restrict__ W2,
                                              const float* __restrict__ b2,
                                              float* __restrict__ out) {
  __shared__ float gr[256];
  __shared__ float t1[128];
  const int b = blockIdx.x, t = threadIdx.x;
  const float inv = 1.0f / fmaxf(cnt[b], 1.0f);
  gr[t] = sums[b * HIDDEN + t] * inv;
  gr[t + 128] = sums[b * HIDDEN + t + 128] * inv;
  __syncthreads();
  float a = b1[t];
  for (int k = 0; k < 256; ++k) a += gr[k] * W1[k * 128 + t];
  t1[t] = fmaxf(a, 0.f);
  __syncthreads();
  float o = b2[t];
  for (int k = 0; k < 128; ++k) o += t1[k] * W2[k * 128 + t];
  out[b * 128 + t] = o;
}

// ---------------------------------------------------------------------------
extern "C" void kernel_launch(void* const* d_in, const int* in_sizes, int n_in,
                              void* d_out, int out_size, void* d_ws,
                              size_t ws_size, hipStream_t stream) {
  (void)n_in;
  (void)ws_size;
  const float* x = (const float*)d_in[0];
  const int* ei = (const int*)d_in[1];
  const int* batch = (const int*)d_in[2];
  const float* W_in = (const float*)d_in[3];
  const float* b_in = (const float*)d_in[4];
  const float* W_g = (const float*)d_in[5];
  const float* b_g = (const float*)d_in[6];
  const float* bn_gamma = (const float*)d_in[7];
  const float* bn_beta = (const float*)d_in[8];
  const float* bn_mean = (const float*)d_in[9];
  const float* bn_var = (const float*)d_in[10];
  const float* W1 = (const float*)d_in[11];
  const float* b1 = (const float*)d_in[12];
  const float* W2 = (const float*)d_in[13];
  const float* b2 = (const float*)d_in[14];

  const int KIN = 768;
  const int N = in_sizes[0] / KIN;   // 100000
  const int E = in_sizes[1] / 2;     // 1600000
  const int G = out_size / 128;      // 64

  const int* src = ei;
  const int* dst = ei + E;

  char* ws = (char*)d_ws;
  size_t off = 0;
  auto take = [&](size_t bytes) -> void* {
    void* p = ws + off;
    off += (bytes + 255) & ~(size_t)255;
    return p;
  };
  float* h0 = (float*)take((size_t)N * HIDDEN * 4);
  unsigned short* h1 = (unsigned short*)take((size_t)N * HIDDEN * 2);  // fp16 m'
  float* dinv = (float*)take((size_t)N * 4);
  int* deg = (int*)take((size_t)N * 4);
  int* fill = (int*)take((size_t)N * 4);
  int* row_ptr = (int*)take((size_t)(N + 1) * 4);
  int* csr = (int*)take((size_t)E * 4);
  float* sums = (float*)take((size_t)G * HIDDEN * 4);
  float* cnt = (float*)take((size_t)G * 4);
  short* Wt = (short*)take((size_t)(393216 + 3 * 131072) * 2);

  hipMemsetAsync(deg, 0, (size_t)N * 4, stream);
  hipMemsetAsync(fill, 0, (size_t)N * 4, stream);
  hipMemsetAsync(sums, 0, (size_t)G * HIDDEN * 4, stream);

  k_prep_w<<<(196608 + 3 * 65536 + 255) / 256, 256, 0, stream>>>(W_in, W_g, Wt);
  k_hist<<<2048, 256, 0, stream>>>(dst, deg, E);
  k_scan<<<1, 1024, 0, stream>>>(deg, row_ptr, N);
  k_dinv<<<(N + 255) / 256, 256, 0, stream>>>(deg, dinv, N);
  k_fill<<<2048, 256, 0, stream>>>(src, dst, row_ptr, fill, csr, E);

  const int gx = (N + 127) / 128;
  gemm_mfma<0><<<gx, 256, 0, stream>>>(x, Wt, b_in, h0, N, KIN);
  for (int i = 0; i < 3; ++i) {
    gemm_mfma<1><<<gx, 256, 0, stream>>>(h0, Wt + 393216 + (size_t)i * 131072,
                                         dinv, (float*)h1, N, HIDDEN);
    k_aggregate<<<(N + 3) / 4, 256, 0, stream>>>(
        h1, row_ptr, csr, dinv, b_g + i * HIDDEN, bn_gamma + i * HIDDEN,
        bn_beta + i * HIDDEN, bn_mean + i * HIDDEN, bn_var + i * HIDDEN, h0, N);
  }
  k_count<<<1, 64, 0, stream>>>(batch, cnt, N, G);
  k_pool<<<(N + 255) / 256, 256, 0, stream>>>(h0, batch, sums, N);
  k_head<<<G, 128, 0, stream>>>(sums, cnt, W1, b1, W2, b2, (float*)d_out);
}